// Round 16
// baseline (239.659 us; speedup 1.0000x reference)
//
#include <hip/hip_runtime.h>

#define IN_CH 512
#define SCAN_BLK 1024

typedef _Float16 f16x8 __attribute__((ext_vector_type(8)));
typedef float f32x4 __attribute__((ext_vector_type(4)));

// async global->LDS, 16B per lane. LDS dest is wave-uniform base + lane*16.
__device__ __forceinline__ void gload_lds16(const void* g, void* l) {
    __builtin_amdgcn_global_load_lds(
        (const __attribute__((address_space(1))) unsigned int*)g,
        (__attribute__((address_space(3))) unsigned int*)l, 16, 0, 0);
}

// ------- merged1: blocks [0,256) = W1 cvt+transpose, rest = degree count (int4) -------
__global__ __launch_bounds__(256) void k_merged1(const float* __restrict__ W1,
                                                 _Float16* __restrict__ W1t,
                                                 const int* __restrict__ col,
                                                 int* __restrict__ deg, int E4, int N) {
    __shared__ float tile[32][33];
    if ((int)blockIdx.x >= 256) {
        int e4 = ((int)blockIdx.x - 256) * 256 + threadIdx.x;
        if (e4 < E4) {
            int4 d4 = ((const int4*)col)[e4];
            if ((unsigned)d4.x < (unsigned)N) atomicAdd(&deg[d4.x], 1);
            if ((unsigned)d4.y < (unsigned)N) atomicAdd(&deg[d4.y], 1);
            if ((unsigned)d4.z < (unsigned)N) atomicAdd(&deg[d4.z], 1);
            if ((unsigned)d4.w < (unsigned)N) atomicAdd(&deg[d4.w], 1);
        }
        return;
    }
    const int bk = (blockIdx.x & 15) * 32, bn = (blockIdx.x >> 4) * 32;
    const int tx = threadIdx.x & 31, ty = threadIdx.x >> 5;   // 32 x 8
#pragma unroll
    for (int p = 0; p < 4; ++p)
        tile[ty + p * 8][tx] = W1[(size_t)(bk + ty + p * 8) * 512 + bn + tx];
    __syncthreads();
#pragma unroll
    for (int p = 0; p < 4; ++p)
        W1t[(size_t)(bn + ty + p * 8) * 512 + bk + tx] = (_Float16)tile[tx][ty + p * 8];
}

// ---- single-kernel scan: each block recomputes ALL tile sums (deg is L2-resident),
// no inter-kernel dependency. Writes rp (exclusive prefix), dis, cursor, rp[N]. ----
__global__ __launch_bounds__(SCAN_BLK) void k_scan(const int* __restrict__ deg,
                                                   int* __restrict__ rp,
                                                   float* __restrict__ dis,
                                                   int* __restrict__ cursor, int N) {
    __shared__ int tsum[64];
    __shared__ int sums[SCAN_BLK];
    __shared__ int boff_s, tot_s;
    const int t = threadIdx.x;
    const int nb = gridDim.x;                 // 49
    const int wv = t >> 6, ln = t & 63;

    // wave wv computes sums of tiles wv, wv+16, wv+32, ...
    for (int j = wv; j < nb; j += 16) {
        int base = j * SCAN_BLK;
        int s = 0;
#pragma unroll
        for (int qq = 0; qq < SCAN_BLK / 64; ++qq) {
            int idx = base + qq * 64 + ln;
            s += (idx < N) ? deg[idx] : 0;
        }
#pragma unroll
        for (int off = 32; off > 0; off >>= 1) s += __shfl_down(s, off);
        if (ln == 0) tsum[j] = s;
    }
    __syncthreads();
    if (t < 64) {
        int v = (t < nb) ? tsum[t] : 0;
        int pre = (t < (int)blockIdx.x) ? v : 0;
        int a = pre, b = v;
#pragma unroll
        for (int off = 32; off > 0; off >>= 1) {
            a += __shfl_down(a, off);
            b += __shfl_down(b, off);
        }
        if (t == 0) { boff_s = a; tot_s = b; }
    }
    int i = blockIdx.x * SCAN_BLK + t;
    int d = (i < N) ? deg[i] : 0;
    sums[t] = d;
    __syncthreads();
    for (int off = 1; off < SCAN_BLK; off <<= 1) {
        int u = (t >= off) ? sums[t - off] : 0;
        __syncthreads();
        sums[t] += u;
        __syncthreads();
    }
    if (i < N) {
        rp[i] = boff_s + sums[t] - d;   // exclusive prefix
        dis[i] = rsqrtf((float)d + 1.0f);
        cursor[i] = 0;
    }
    if (blockIdx.x == gridDim.x - 1 && t == 0) rp[N] = tot_s;
}

// ------- merged2: blocks [0,nwg) = 128x256 fused-cvt MFMA GEMM, rest = CSR fill -------
// R15 structure + T14 A-prefetch (R14-verified): next K-step's A float4s issued right
// after barrier #1 so their latency hides under the MFMA section. Both LDS operands
// conflict-free via the XOR involution. Epilogue prescales y rows by dis[m].
__global__ __launch_bounds__(512, 4) void k_merged2(const float* __restrict__ A,
                                                    const _Float16* __restrict__ Bt,
                                                    const float* __restrict__ dis,
                                                    _Float16* __restrict__ C,
                                                    int Nrows, int nbm, int nwg,
                                                    const int* __restrict__ ei,
                                                    const int* __restrict__ rp,
                                                    int* __restrict__ cursor,
                                                    int* __restrict__ csrc,
                                                    int E, int N) {
    __shared__ __align__(16) _Float16 As[128 * 64];   // 16 KB
    __shared__ __align__(16) _Float16 Bs[256 * 64];   // 32 KB

    if ((int)blockIdx.x >= nwg) {
        int e = ((int)blockIdx.x - nwg) * 512 + threadIdx.x;
        if (e < E) {
            int s = ei[e];
            int d = ei[E + e];
            if ((unsigned)s < (unsigned)N && (unsigned)d < (unsigned)N) {
                int pos = atomicAdd(&cursor[d], 1);
                csrc[rp[d] + pos] = s;
            }
        }
        return;
    }

    // ---- GEMM: y = dis * (cvt16(x) @ W1t^T), tile 128x256 ----
    const int g = (int)blockIdx.x;
    const int t = threadIdx.x;
    const int lane = t & 63, w = t >> 6;           // 8 waves
    const int wm = w >> 2, wn = w & 3;             // 2x4 wave grid

    const int q = nwg >> 3, r = nwg & 7;
    const int xcd = g & 7, within = g >> 3;
    const int wg = (xcd < r ? xcd * (q + 1) : r * (q + 1) + (xcd - r) * q) + within;
    const int bm = (wg >> 1) * 128, bn = (wg & 1) * 256;

    const int rr = lane & 15, kg = lane >> 4;
    const int lrow = lane >> 3;                    // B staging row-in-8
    const int scol = ((lane & 7) ^ lrow) * 8;      // B pre-swizzled source col
    const int rsw = rr & 7;                        // read-side row swizzle
    const int arow = t >> 3;                       // A staging row (0..63)
    const int achk = t & 7;                        // A LDS chunk
    const int agcol = (achk ^ (arow & 7)) * 8;     // A swizzled global col

    const float* Abase[2];
#pragma unroll
    for (int p = 0; p < 2; ++p) {
        int grow = bm + p * 64 + arow;
        if (grow >= Nrows) grow = Nrows - 1;
        Abase[p] = A + (size_t)grow * 512 + agcol;
    }
    // T14: prefetch first A tile into regs
    float4 pa[2], pb[2];
#pragma unroll
    for (int p = 0; p < 2; ++p) {
        pa[p] = *(const float4*)(Abase[p]);
        pb[p] = *(const float4*)(Abase[p] + 4);
    }

    f32x4 acc[4][4];
#pragma unroll
    for (int i = 0; i < 4; ++i)
#pragma unroll
        for (int j = 0; j < 4; ++j) acc[i][j] = (f32x4)0.0f;

    for (int k0 = 0; k0 < 512; k0 += 64) {
        // B tile (256x64) via async DMA, pre-swizzled source: 4 issues/wave
#pragma unroll
        for (int p = 0; p < 4; ++p) {
            const int row = p * 64 + w * 8 + lrow;
            gload_lds16(Bt + (size_t)(bn + row) * 512 + k0 + scol,
                        Bs + (p * 64 + w * 8) * 64);
        }
        // A tile (128x64): cvt prefetched regs -> swizzled ds_write (2 rows/thread)
#pragma unroll
        for (int p = 0; p < 2; ++p) {
            f16x8 o;
            o[0] = (_Float16)pa[p].x; o[1] = (_Float16)pa[p].y;
            o[2] = (_Float16)pa[p].z; o[3] = (_Float16)pa[p].w;
            o[4] = (_Float16)pb[p].x; o[5] = (_Float16)pb[p].y;
            o[6] = (_Float16)pb[p].z; o[7] = (_Float16)pb[p].w;
            *(f16x8*)(As + (p * 64 + arow) * 64 + achk * 8) = o;
        }
        __syncthreads();
        // issue next A loads NOW -> latency hides under the MFMA section
        if (k0 + 64 < 512) {
#pragma unroll
            for (int p = 0; p < 2; ++p) {
                pa[p] = *(const float4*)(Abase[p] + k0 + 64);
                pb[p] = *(const float4*)(Abase[p] + k0 + 68);
            }
        }
#pragma unroll
        for (int kk = 0; kk < 2; ++kk) {
            f16x8 a[4], b[4];
#pragma unroll
            for (int i = 0; i < 4; ++i)
                a[i] = *(const f16x8*)(As + (wm * 64 + i * 16 + rr) * 64 +
                                       (((kk << 2) + kg) ^ rsw) * 8);
#pragma unroll
            for (int j = 0; j < 4; ++j)
                b[j] = *(const f16x8*)(Bs + (wn * 64 + j * 16 + rr) * 64 +
                                       (((kk << 2) + kg) ^ rsw) * 8);
#pragma unroll
            for (int i = 0; i < 4; ++i)
#pragma unroll
                for (int j = 0; j < 4; ++j)
                    acc[i][j] = __builtin_amdgcn_mfma_f32_16x16x32_f16(a[i], b[j], acc[i][j], 0, 0, 0);
        }
        __syncthreads();
    }

    // C/D layout: col = lane&15, row = (lane>>4)*4 + reg. Prescale row by dis[m].
#pragma unroll
    for (int i = 0; i < 4; ++i)
#pragma unroll
        for (int reg = 0; reg < 4; ++reg) {
            int m = bm + wm * 64 + i * 16 + kg * 4 + reg;
            int mc = (m < Nrows) ? m : Nrows - 1;
            float dm = dis[mc];
#pragma unroll
            for (int j = 0; j < 4; ++j) {
                int n = bn + wn * 64 + j * 16 + rr;
                C[(size_t)m * 512 + n] = (_Float16)(acc[i][j][reg] * dm);
            }
        }
}

// ---------------- layer-1 aggregation (R7/R14 form: y prescaled by dis) ----------------
// ~3.65 TB/s cross-L2/L3-fabric gather floor (R8-R15 stable, 8 configs). Frozen.
__global__ __launch_bounds__(256) void k_agg(const _Float16* __restrict__ y,
                                             const float* __restrict__ dis,
                                             const int* __restrict__ rp,
                                             const int* __restrict__ csrc,
                                             const float* __restrict__ b1,
                                             const float* __restrict__ W2,
                                             float* __restrict__ z, int N) {
    const int n = blockIdx.x * 4 + (threadIdx.x >> 6);
    if (n >= N) return;
    const int l = threadIdx.x & 63;

    const float d1 = dis[n];
    f16x8 self = *(const f16x8*)(y + (size_t)n * 512 + l * 8);
    float acc[8];
#pragma unroll
    for (int c = 0; c < 8; ++c) acc[c] = (float)self[c];

    int j = rp[n], jend = rp[n + 1];
    for (; j + 8 <= jend; j += 8) {
        int s[8]; f16x8 v[8];
#pragma unroll
        for (int u = 0; u < 8; ++u) s[u] = csrc[j + u];
#pragma unroll
        for (int u = 0; u < 8; ++u)
            v[u] = *(const f16x8*)(y + (size_t)s[u] * 512 + l * 8);
#pragma unroll
        for (int u = 0; u < 8; ++u)
#pragma unroll
            for (int c = 0; c < 8; ++c) acc[c] += (float)v[u][c];
    }
    for (; j + 2 <= jend; j += 2) {
        int s0 = csrc[j], s1 = csrc[j + 1];
        f16x8 v0 = *(const f16x8*)(y + (size_t)s0 * 512 + l * 8);
        f16x8 v1 = *(const f16x8*)(y + (size_t)s1 * 512 + l * 8);
#pragma unroll
        for (int c = 0; c < 8; ++c) acc[c] += (float)v0[c] + (float)v1[c];
    }
    if (j < jend) {
        f16x8 v0 = *(const f16x8*)(y + (size_t)csrc[j] * 512 + l * 8);
#pragma unroll
        for (int c = 0; c < 8; ++c) acc[c] += (float)v0[c];
    }

    float4 bb0 = *(const float4*)(b1 + l * 8);
    float4 bb1 = *(const float4*)(b1 + l * 8 + 4);
    float4 w20 = *(const float4*)(W2 + l * 8);
    float4 w21 = *(const float4*)(W2 + l * 8 + 4);
    float bbv[8] = {bb0.x, bb0.y, bb0.z, bb0.w, bb1.x, bb1.y, bb1.z, bb1.w};
    float w2v[8] = {w20.x, w20.y, w20.z, w20.w, w21.x, w21.y, w21.z, w21.w};
    float p = 0.0f;
#pragma unroll
    for (int c = 0; c < 8; ++c) {
        float h = fmaxf(acc[c] * d1 + bbv[c], 0.0f);
        p += h * w2v[c];
    }
#pragma unroll
    for (int off = 32; off > 0; off >>= 1) p += __shfl_down(p, off);
    if (l == 0) z[n] = d1 * p;
}

// ---------------- layer-2 aggregation on prescaled scalars ----------------
__global__ void k_out(const float* __restrict__ z, const float* __restrict__ dis,
                      const int* __restrict__ rp, const int* __restrict__ csrc,
                      const float* __restrict__ b2, float* __restrict__ out, int N) {
    int n = blockIdx.x * blockDim.x + threadIdx.x;
    if (n >= N) return;
    float acc = z[n];
    int j = rp[n], jend = rp[n + 1];
    for (; j + 4 <= jend; j += 4) {
        float a0 = z[csrc[j]];
        float a1 = z[csrc[j + 1]];
        float a2 = z[csrc[j + 2]];
        float a3 = z[csrc[j + 3]];
        acc += (a0 + a1) + (a2 + a3);
    }
    for (; j < jend; ++j) acc += z[csrc[j]];
    out[n] = dis[n] * acc + b2[0];
}

extern "C" void kernel_launch(void* const* d_in, const int* in_sizes, int n_in,
                              void* d_out, int out_size, void* d_ws, size_t ws_size,
                              hipStream_t stream) {
    const float* x  = (const float*)d_in[0];
    const int*   ei = (const int*)d_in[1];
    const float* W1 = (const float*)d_in[2];
    const float* b1 = (const float*)d_in[3];
    const float* W2 = (const float*)d_in[4];
    const float* b2 = (const float*)d_in[5];
    float* out = (float*)d_out;

    const int N = in_sizes[0] / IN_CH;            // 50000
    const int E = in_sizes[1] / 2;                // 800000
    const int nbm = (N + 127) / 128;              // 391
    const int M2 = nbm * 128;                     // 50048
    const int NB = (N + SCAN_BLK - 1) / SCAN_BLK; // 49 (<= 64 for k_scan)
    const int E4 = E / 4;                         // 200000 (E % 4 == 0)
    const int DEGB4 = (E4 + 255) / 256;           // 782
    const int FILLB = (E + 511) / 512;            // 1563 (merged2, 512 thr)
    const int nwg   = nbm * 2;                    // 782

    char* ws = (char*)d_ws;
    size_t off = 0;
    auto alloc = [&](size_t bytes) {
        char* p = ws + off;
        off += (bytes + 255) & ~(size_t)255;
        return p;
    };
    _Float16* y   = (_Float16*)alloc((size_t)M2 * 512 * sizeof(_Float16)); // 51.25 MB
    _Float16* W1t = (_Float16*)alloc((size_t)512 * 512 * sizeof(_Float16));
    int*   deg    = (int*)alloc((size_t)N * sizeof(int));
    float* dis    = (float*)alloc((size_t)N * sizeof(float));
    int*   rp     = (int*)alloc((size_t)(N + 1) * sizeof(int));
    int*   cursor = (int*)alloc((size_t)N * sizeof(int));
    int*   csrc   = (int*)alloc((size_t)E * sizeof(int));
    float* z      = (float*)alloc((size_t)N * sizeof(float));

    hipMemsetAsync(deg, 0, (size_t)N * sizeof(int), stream);

    k_merged1<<<256 + DEGB4, 256, 0, stream>>>(W1, W1t, ei + E, deg, E4, N);
    k_scan<<<NB, SCAN_BLK, 0, stream>>>(deg, rp, dis, cursor, N);
    k_merged2<<<nwg + FILLB, 512, 0, stream>>>(x, W1t, dis, y, N, nbm, nwg,
                                               ei, rp, cursor, csrc, E, N);
    k_agg<<<(N + 3) / 4, 256, 0, stream>>>(y, dis, rp, csrc, b1, W2, z, N);
    k_out<<<(N + 255) / 256, 256, 0, stream>>>(z, dis, rp, csrc, b2, out, N);
}